// Round 7
// baseline (55.128 us; speedup 1.0000x reference)
//
#include <hip/hip_runtime.h>

typedef float v2f __attribute__((ext_vector_type(2)));

#define N 512
#define P 2
#define DX 128
#define CLAMP_C 1e-4f
#define LOG2E_C 1.4426950408889634f
#define LN2_C 0.6931471805599453f
#define LOG2PI_C 1.8378770664093453f

#define NQ 8                 // j-values per block (16 output streams)
#define NCHUNK 16            // i-chunks (32 rows each)

// ws float offsets
#define WS_EDX    0          // 65536: exp(-d[i,k]), [i][k] (k=127 pad, masked)
#define WS_EU     65536      // 131072: exp(-u[jd,k]) with jd=j*2+dz
#define WS_PART   196608     // 16384: [(jt*16+o)][c] log2-partials
#define WS_C0P    212992     // 256: per-block partial of sum (1-x~)*d
#define WS_T0P    213248     // 256: partial of sum (1-x~)*theta0[k+1]
#define WS_T1P    213504     // 256: partial of sum (1-x~)*theta1[k+1]
#define WS_S0     213760     // 1
#define WS_TICKET 213764     // 64 ints

#define EXP2F(v) __builtin_amdgcn_exp2f(v)

__device__ __forceinline__ v2f splat2(float a) { v2f r; r.x = a; r.y = a; return r; }

// log2(m) for m in [1,2): deg-5 Taylor @1.5, |err| <= ~4.6e-4 (budget ~1e5)
__device__ __forceinline__ float log2s(float m) {
    const float t = m - 1.5f;
    float p = t * 0.03799691f + -0.07124420f;
    p = p * t + 0.14248840f;
    p = p * t + -0.32059890f;
    p = p * t + 0.96179669f;
    p = p * t + 0.58496250f;
    return p;
}

// strip exponent into integer accumulator, renormalize mantissa to [1,2)
__device__ __forceinline__ float strip_add(float v, int& acc) {
    const unsigned b = __float_as_uint(v);
    acc += (int)(b >> 23);                         // biased; bias removed at end
    return __uint_as_float((b & 0x007fffffu) | 0x3f800000u);
}

// prep: edx table + eu table + C0/T0/T1 block-partials + S0 + zero tickets
__global__ __launch_bounds__(256)
void prep_kernel(const float* __restrict__ z, const float* __restrict__ x,
                 const float* __restrict__ theta, float* __restrict__ ws) {
    const int tid = threadIdx.x;
    const int gid = blockIdx.x * 256 + tid;
    if (blockIdx.x == 0 && tid < 64) ((int*)(ws + WS_TICKET))[tid] = 0;

    if (blockIdx.x < 256) {                        // edx region: gid < 65536
        const int i = gid >> 7, k = gid & 127;
        const float* xr = x + i * DX;
        // d[i,k] = sum_m 0.1^(m+1) x[i,k-m]; taps < 1e-7 dropped
        float d = 0.1f * xr[k];
        if (k >= 1) d = __builtin_fmaf(1e-2f, xr[k - 1], d);
        if (k >= 2) d = __builtin_fmaf(1e-3f, xr[k - 2], d);
        if (k >= 3) d = __builtin_fmaf(1e-4f, xr[k - 3], d);
        if (k >= 4) d = __builtin_fmaf(1e-5f, xr[k - 4], d);
        if (k >= 5) d = __builtin_fmaf(1e-6f, xr[k - 5], d);
        ws[WS_EDX + gid] = EXP2F(-d * LOG2E_C);    // exp(-d), positive

        // weighted partials for the linear term (k=127 pad contributes 0)
        const int kc = (k < 127) ? k + 1 : 127;
        const float w = (k < 127) ? (1.f - xr[kc]) : 0.f;
        float c0 = w * d;
        float t0 = w * theta[kc];
        float t1 = w * theta[DX + kc];
        #pragma unroll
        for (int off = 32; off > 0; off >>= 1) {
            c0 += __shfl_xor(c0, off, 64);
            t0 += __shfl_xor(t0, off, 64);
            t1 += __shfl_xor(t1, off, 64);
        }
        __shared__ float rbuf[4][3];
        if ((tid & 63) == 0) {
            rbuf[tid >> 6][0] = c0; rbuf[tid >> 6][1] = t0; rbuf[tid >> 6][2] = t1;
        }
        __syncthreads();
        if (tid == 0) {
            ws[WS_C0P + blockIdx.x] = rbuf[0][0] + rbuf[1][0] + rbuf[2][0] + rbuf[3][0];
            ws[WS_T0P + blockIdx.x] = rbuf[0][1] + rbuf[1][1] + rbuf[2][1] + rbuf[3][1];
            ws[WS_T1P + blockIdx.x] = rbuf[0][2] + rbuf[1][2] + rbuf[2][2] + rbuf[3][2];
        }
    } else {                                       // eu region
        const int t = gid - 65536;                 // [0, 131072)
        const int jd = t >> 7, k = t & 127;
        const int kc = (k < 127) ? (k + 1) : 127;  // pad clamped (masked later)
        const float th0 = theta[kc] * LOG2E_C;
        const float th1 = theta[DX + kc] * LOG2E_C;
        ws[WS_EU + t] = EXP2F(-(z[jd * 2] * th0 + z[jd * 2 + 1] * th1));

        if (blockIdx.x == 767) {                   // S0 = sum_i x[i,0]
            float s0 = x[tid * DX] + x[(tid + 256) * DX];
            #pragma unroll
            for (int off = 32; off > 0; off >>= 1) s0 += __shfl_xor(s0, off, 64);
            __shared__ float sbuf[4];
            if ((tid & 63) == 0) sbuf[tid >> 6] = s0;
            __syncthreads();
            if (tid == 0) ws[WS_S0] = sbuf[0] + sbuf[1] + sbuf[2] + sbuf[3];
        }
    }
}

// main: den-only product via quad-grouped Horner + ticket-based inline finalize
__global__ __launch_bounds__(256, 4)
void main_kernel(const float* __restrict__ z, const float* __restrict__ theta,
                 float* __restrict__ ws, float* __restrict__ out) {
    const int jt = blockIdx.x >> 4;            // 0..63
    const int c  = blockIdx.x & 15;            // 0..15
    const int j0 = jt * NQ;
    const int i0 = c * 32;
    const int tid  = threadIdx.x;
    const int ke   = tid & 127;
    const int half = tid >> 7;
    const bool valid = (ke < 127);

    const float* eub = ws + WS_EU + j0 * 256 + ke;
    v2f eu[NQ];
    #pragma unroll
    for (int q = 0; q < NQ; ++q) {             // {dz0, dz1} of j0+q
        eu[q].x = eub[q * 256];
        eu[q].y = eub[q * 256 + 128];
    }

    const float* ep = ws + WS_EDX + (i0 + half * 16) * 128 + ke;
    v2f den[NQ];
    int accX[NQ], accY[NQ];
    #pragma unroll
    for (int q = 0; q < NQ; ++q) { den[q] = splat2(1.f); accX[q] = 0; accY[q] = 0; }

    // 4 quads of 4 rows: prod (1 + ed_r*eu) = deg-4 poly in eu (Horner),
    // coefficients shared across all 16 streams. Strip every 8 rows
    // (e < 1e4 guaranteed by reference finiteness -> product <= 1e32).
    #pragma unroll
    for (int qd = 0; qd < 4; ++qd) {
        const float e0 = ep[(qd * 4 + 0) * 128];
        const float e1 = ep[(qd * 4 + 1) * 128];
        const float e2 = ep[(qd * 4 + 2) * 128];
        const float e3 = ep[(qd * 4 + 3) * 128];
        const float A1 = e0 * e1, B1 = e0 + e1;
        const float A2 = e2 * e3, B2 = e2 + e3;
        const float d4 = A1 * A2;
        const float d3 = __builtin_fmaf(B1, A2, A1 * B2);
        const float d2 = __builtin_fmaf(B1, B2, A1 + A2);
        const float d1 = B1 + B2;
        const v2f v4 = splat2(d4), v3 = splat2(d3), v2 = splat2(d2), v1 = splat2(d1);
        #pragma unroll
        for (int q = 0; q < NQ; ++q) {
            v2f t = v4 * eu[q] + v3;
            t = t * eu[q] + v2;
            t = t * eu[q] + v1;
            t = t * eu[q] + splat2(1.f);
            den[q] *= t;
        }
        if (qd & 1) {
            #pragma unroll
            for (int q = 0; q < NQ; ++q) {
                den[q].x = strip_add(den[q].x, accX[q]);
                den[q].y = strip_add(den[q].y, accY[q]);
            }
        }
    }

    // per-thread finalize: log2(den_chunk) = (acc - 2*127) + poly(m); reduce
    __shared__ float red[4][16];
    #pragma unroll
    for (int q = 0; q < NQ; ++q) {
        float vx = valid ? ((float)(accX[q] - 254) + log2s(den[q].x)) : 0.f;
        float vy = valid ? ((float)(accY[q] - 254) + log2s(den[q].y)) : 0.f;
        #pragma unroll
        for (int off = 32; off > 0; off >>= 1) {
            vx += __shfl_xor(vx, off, 64);
            vy += __shfl_xor(vy, off, 64);
        }
        if ((tid & 63) == 0) { red[tid >> 6][2 * q] = vx; red[tid >> 6][2 * q + 1] = vy; }
    }
    __syncthreads();
    if (tid < 16) {
        const float t = red[0][tid] + red[1][tid] + red[2][tid] + red[3][tid];
        __hip_atomic_store(&ws[WS_PART + (jt * 16 + tid) * 16 + c], t,
                           __ATOMIC_RELEASE, __HIP_MEMORY_SCOPE_AGENT);
    }
    __syncthreads();                           // drains all stores (vmcnt before barrier)

    __shared__ int winner;
    if (tid == 0) {
        int* tk = (int*)(ws + WS_TICKET);
        winner = (__hip_atomic_fetch_add(tk + jt, 1, __ATOMIC_ACQ_REL,
                                         __HIP_MEMORY_SCOPE_AGENT) == 15);
    }
    __syncthreads();
    if (!winner) return;

    // ---- finalize this jt's 16 outputs (16th arriver) ----
    float c0 = ws[WS_C0P + tid];               // prep outputs: kernel-boundary coherent
    float t0 = ws[WS_T0P + tid];
    float t1 = ws[WS_T1P + tid];
    #pragma unroll
    for (int off = 32; off > 0; off >>= 1) {
        c0 += __shfl_xor(c0, off, 64);
        t0 += __shfl_xor(t0, off, 64);
        t1 += __shfl_xor(t1, off, 64);
    }
    __shared__ float fbuf[4][3];
    if ((tid & 63) == 0) { fbuf[tid >> 6][0] = c0; fbuf[tid >> 6][1] = t0; fbuf[tid >> 6][2] = t1; }
    __syncthreads();
    const float C0 = fbuf[0][0] + fbuf[1][0] + fbuf[2][0] + fbuf[3][0];
    const float T0 = fbuf[0][1] + fbuf[1][1] + fbuf[2][1] + fbuf[3][1];
    const float T1 = fbuf[0][2] + fbuf[1][2] + fbuf[2][2] + fbuf[3][2];

    if (tid < 16) {
        const int j = j0 + (tid >> 1), dz = tid & 1;
        const float z0 = z[j * 4 + dz * 2];
        const float z1 = z[j * 4 + dz * 2 + 1];

        float sp = 0.f;                        // sum of log2(1+e) partials
        #pragma unroll
        for (int cc = 0; cc < 16; ++cc)
            sp += __hip_atomic_load(&ws[WS_PART + (jt * 16 + tid) * 16 + cc],
                                    __ATOMIC_ACQUIRE, __HIP_MEMORY_SCOPE_AGENT);

        // lp = logpdf(z0,1e-3) + logpdf(z1,exp(z0/4)); log(exp(z0/4)) == z0/4
        const float u1 = z0 * 1000.f;
        const float e4 = __expf(-z0 * 0.25f);
        const float u2 = z1 * e4;
        const float lp = -0.5f * u1 * u1 + 6.9077552790f
                       - 0.5f * u2 * u2 - z0 * 0.25f - LOG2PI_C;

        // lp0 (exact, clamped)
        const float S0  = ws[WS_S0];
        const float up0 = z0 * theta[0] + z1 * theta[DX];
        const float p0  = 1.f / (1.f + __expf(-up0));
        const float lp0 = __logf(p0 - CLAMP_C) * S0
                        + __logf(1.f - p0 + CLAMP_C) * ((float)N - S0);

        // term sum = -SP*ln2 - (C0 + z0*T0 + z1*T1)
        out[j * 2 + dz] = lp + lp0 - sp * LN2_C
                        - (C0 + z0 * T0 + z1 * T1);
    }
}

extern "C" void kernel_launch(void* const* d_in, const int* in_sizes, int n_in,
                              void* d_out, int out_size, void* d_ws, size_t ws_size,
                              hipStream_t stream) {
    const float* z     = (const float*)d_in[0];   // (512, 2, 2)
    const float* x     = (const float*)d_in[1];   // (512, 128)
    const float* theta = (const float*)d_in[2];   // (2, 128)
    float* ws  = (float*)d_ws;
    float* out = (float*)d_out;                   // (512, 2) float32

    hipLaunchKernelGGL(prep_kernel, dim3(768),  dim3(256), 0, stream, z, x, theta, ws);
    hipLaunchKernelGGL(main_kernel, dim3(1024), dim3(256), 0, stream, z, theta, ws, out);
}

// Round 8
// 19.604 us; speedup vs baseline: 2.8121x; 2.8121x over previous
//
#include <hip/hip_runtime.h>

typedef float v2f __attribute__((ext_vector_type(2)));

#define N 512
#define P 2
#define DX 128
#define CLAMP_C 1e-4f
#define LOG2E_C 1.4426950408889634f
#define LN2_C 0.6931471805599453f
#define LOG2PI_C 1.8378770664093453f

#define NQ 8                 // j-values per block (16 output streams)

// ws float offsets
#define WS_EDX    0          // 65536: exp(-d[i,k]), [i][k] (k=127 pad, masked)
#define WS_EU     65536      // 131072: exp(-u[jd,k]) with jd=j*2+dz
#define WS_PART   196608     // 16384: [(jt*16+o)][c] log2-partials
#define WS_C0P    212992     // 256: per-block partial of sum (1-x~)*d
#define WS_T0P    213248     // 256: partial of sum (1-x~)*theta0[k+1]
#define WS_T1P    213504     // 256: partial of sum (1-x~)*theta1[k+1]
#define WS_S0     213760     // 1

#define EXP2F(v) __builtin_amdgcn_exp2f(v)

__device__ __forceinline__ v2f splat2(float a) { v2f r; r.x = a; r.y = a; return r; }

// log2(m) for m in [1,2): deg-5 Taylor @1.5, |err| <= ~4.6e-4 (budget ~1e5)
__device__ __forceinline__ float log2s(float m) {
    const float t = m - 1.5f;
    float p = t * 0.03799691f + -0.07124420f;
    p = p * t + 0.14248840f;
    p = p * t + -0.32059890f;
    p = p * t + 0.96179669f;
    p = p * t + 0.58496250f;
    return p;
}

// strip exponent into integer accumulator, renormalize mantissa to [1,2)
__device__ __forceinline__ float strip_add(float v, int& acc) {
    const unsigned b = __float_as_uint(v);
    acc += (int)(b >> 23);                         // biased; bias removed at end
    return __uint_as_float((b & 0x007fffffu) | 0x3f800000u);
}

// prep: edx table + eu table + C0/T0/T1 block-partials + S0
__global__ __launch_bounds__(256)
void prep_kernel(const float* __restrict__ z, const float* __restrict__ x,
                 const float* __restrict__ theta, float* __restrict__ ws) {
    const int tid = threadIdx.x;
    const int gid = blockIdx.x * 256 + tid;

    if (blockIdx.x < 256) {                        // edx region: gid < 65536
        const int i = gid >> 7, k = gid & 127;
        const float* xr = x + i * DX;
        // d[i,k] = sum_m 0.1^(m+1) x[i,k-m]; taps < 1e-7 dropped
        float d = 0.1f * xr[k];
        if (k >= 1) d = __builtin_fmaf(1e-2f, xr[k - 1], d);
        if (k >= 2) d = __builtin_fmaf(1e-3f, xr[k - 2], d);
        if (k >= 3) d = __builtin_fmaf(1e-4f, xr[k - 3], d);
        if (k >= 4) d = __builtin_fmaf(1e-5f, xr[k - 4], d);
        if (k >= 5) d = __builtin_fmaf(1e-6f, xr[k - 5], d);
        ws[WS_EDX + gid] = EXP2F(-d * LOG2E_C);    // exp(-d), positive

        // weighted partials for the linear term (k=127 pad contributes 0)
        const int kc = (k < 127) ? k + 1 : 127;
        const float w = (k < 127) ? (1.f - xr[kc]) : 0.f;
        float c0 = w * d;
        float t0 = w * theta[kc];
        float t1 = w * theta[DX + kc];
        #pragma unroll
        for (int off = 32; off > 0; off >>= 1) {
            c0 += __shfl_xor(c0, off, 64);
            t0 += __shfl_xor(t0, off, 64);
            t1 += __shfl_xor(t1, off, 64);
        }
        __shared__ float rbuf[4][3];
        if ((tid & 63) == 0) {
            rbuf[tid >> 6][0] = c0; rbuf[tid >> 6][1] = t0; rbuf[tid >> 6][2] = t1;
        }
        __syncthreads();
        if (tid == 0) {
            ws[WS_C0P + blockIdx.x] = rbuf[0][0] + rbuf[1][0] + rbuf[2][0] + rbuf[3][0];
            ws[WS_T0P + blockIdx.x] = rbuf[0][1] + rbuf[1][1] + rbuf[2][1] + rbuf[3][1];
            ws[WS_T1P + blockIdx.x] = rbuf[0][2] + rbuf[1][2] + rbuf[2][2] + rbuf[3][2];
        }
    } else {                                       // eu region
        const int t = gid - 65536;                 // [0, 131072)
        const int jd = t >> 7, k = t & 127;
        const int kc = (k < 127) ? (k + 1) : 127;  // pad clamped (masked later)
        const float th0 = theta[kc] * LOG2E_C;
        const float th1 = theta[DX + kc] * LOG2E_C;
        ws[WS_EU + t] = EXP2F(-(z[jd * 2] * th0 + z[jd * 2 + 1] * th1));

        if (blockIdx.x == 767) {                   // S0 = sum_i x[i,0]
            float s0 = x[tid * DX] + x[(tid + 256) * DX];
            #pragma unroll
            for (int off = 32; off > 0; off >>= 1) s0 += __shfl_xor(s0, off, 64);
            __shared__ float sbuf[4];
            if ((tid & 63) == 0) sbuf[tid >> 6] = s0;
            __syncthreads();
            if (tid == 0) ws[WS_S0] = sbuf[0] + sbuf[1] + sbuf[2] + sbuf[3];
        }
    }
}

// main: den-only product via quad-grouped Horner; plain partial stores
__global__ __launch_bounds__(256, 4)
void main_kernel(float* __restrict__ ws) {
    const int jt = blockIdx.x >> 4;            // 0..63
    const int c  = blockIdx.x & 15;            // 0..15
    const int j0 = jt * NQ;
    const int i0 = c * 32;
    const int tid  = threadIdx.x;
    const int ke   = tid & 127;
    const int half = tid >> 7;
    const bool valid = (ke < 127);

    const float* eub = ws + WS_EU + j0 * 256 + ke;
    v2f eu[NQ];
    #pragma unroll
    for (int q = 0; q < NQ; ++q) {             // {dz0, dz1} of j0+q
        eu[q].x = eub[q * 256];
        eu[q].y = eub[q * 256 + 128];
    }

    const float* ep = ws + WS_EDX + (i0 + half * 16) * 128 + ke;
    v2f den[NQ];
    int accX[NQ], accY[NQ];
    #pragma unroll
    for (int q = 0; q < NQ; ++q) { den[q] = splat2(1.f); accX[q] = 0; accY[q] = 0; }

    // 4 quads of 4 rows: prod (1 + ed_r*eu) = deg-4 poly in eu (Horner),
    // coefficients shared across all 16 streams. Strip every 8 rows.
    #pragma unroll
    for (int qd = 0; qd < 4; ++qd) {
        const float e0 = ep[(qd * 4 + 0) * 128];
        const float e1 = ep[(qd * 4 + 1) * 128];
        const float e2 = ep[(qd * 4 + 2) * 128];
        const float e3 = ep[(qd * 4 + 3) * 128];
        const float A1 = e0 * e1, B1 = e0 + e1;
        const float A2 = e2 * e3, B2 = e2 + e3;
        const float d4 = A1 * A2;
        const float d3 = __builtin_fmaf(B1, A2, A1 * B2);
        const float d2 = __builtin_fmaf(B1, B2, A1 + A2);
        const float d1 = B1 + B2;
        const v2f v4 = splat2(d4), v3 = splat2(d3), v2 = splat2(d2), v1 = splat2(d1);
        #pragma unroll
        for (int q = 0; q < NQ; ++q) {
            v2f t = v4 * eu[q] + v3;
            t = t * eu[q] + v2;
            t = t * eu[q] + v1;
            t = t * eu[q] + splat2(1.f);
            den[q] *= t;
        }
        if (qd & 1) {
            #pragma unroll
            for (int q = 0; q < NQ; ++q) {
                den[q].x = strip_add(den[q].x, accX[q]);
                den[q].y = strip_add(den[q].y, accY[q]);
            }
        }
    }

    // per-thread finalize: log2(den_chunk) = (acc - 2*127) + poly(m); reduce
    __shared__ float red[4][16];
    #pragma unroll
    for (int q = 0; q < NQ; ++q) {
        float vx = valid ? ((float)(accX[q] - 254) + log2s(den[q].x)) : 0.f;
        float vy = valid ? ((float)(accY[q] - 254) + log2s(den[q].y)) : 0.f;
        #pragma unroll
        for (int off = 32; off > 0; off >>= 1) {
            vx += __shfl_xor(vx, off, 64);
            vy += __shfl_xor(vy, off, 64);
        }
        if ((tid & 63) == 0) { red[tid >> 6][2 * q] = vx; red[tid >> 6][2 * q + 1] = vy; }
    }
    __syncthreads();
    if (tid < 16) {
        const float t = red[0][tid] + red[1][tid] + red[2][tid] + red[3][tid];
        ws[WS_PART + (jt * 16 + tid) * 16 + c] = t;    // plain store
    }
}

__global__ __launch_bounds__(256)
void final_kernel(const float* __restrict__ z, const float* __restrict__ theta,
                  const float* __restrict__ ws, float* __restrict__ out) {
    const int tid = threadIdx.x;

    // redundant per-block reduce of C0/T0/T1 partials (256 floats each, L2-hit)
    float c0 = ws[WS_C0P + tid];
    float t0 = ws[WS_T0P + tid];
    float t1 = ws[WS_T1P + tid];
    #pragma unroll
    for (int off = 32; off > 0; off >>= 1) {
        c0 += __shfl_xor(c0, off, 64);
        t0 += __shfl_xor(t0, off, 64);
        t1 += __shfl_xor(t1, off, 64);
    }
    __shared__ float fbuf[4][3];
    if ((tid & 63) == 0) { fbuf[tid >> 6][0] = c0; fbuf[tid >> 6][1] = t0; fbuf[tid >> 6][2] = t1; }
    __syncthreads();
    const float C0 = fbuf[0][0] + fbuf[1][0] + fbuf[2][0] + fbuf[3][0];
    const float T0 = fbuf[0][1] + fbuf[1][1] + fbuf[2][1] + fbuf[3][1];
    const float T1 = fbuf[0][2] + fbuf[1][2] + fbuf[2][2] + fbuf[3][2];

    const int gid = blockIdx.x * 256 + tid;    // grid 4*256 = N*P
    const int j = gid >> 1, dz = gid & 1;
    const int jt = j >> 3, o = (j & 7) * 2 + dz;
    const float z0 = z[j * 4 + dz * 2];
    const float z1 = z[j * 4 + dz * 2 + 1];

    float sp = 0.f;                            // sum of log2(1+e) partials
    #pragma unroll
    for (int cc = 0; cc < 16; ++cc)
        sp += ws[WS_PART + (jt * 16 + o) * 16 + cc];

    // lp = logpdf(z0,1e-3) + logpdf(z1,exp(z0/4)); log(exp(z0/4)) == z0/4
    const float u1 = z0 * 1000.f;
    const float e4 = __expf(-z0 * 0.25f);
    const float u2 = z1 * e4;
    const float lp = -0.5f * u1 * u1 + 6.9077552790f
                   - 0.5f * u2 * u2 - z0 * 0.25f - LOG2PI_C;

    // lp0 (exact, clamped)
    const float S0  = ws[WS_S0];
    const float up0 = z0 * theta[0] + z1 * theta[DX];
    const float p0  = 1.f / (1.f + __expf(-up0));
    const float lp0 = __logf(p0 - CLAMP_C) * S0
                    + __logf(1.f - p0 + CLAMP_C) * ((float)N - S0);

    // term sum = -SP*ln2 - (C0 + z0*T0 + z1*T1)
    out[j * 2 + dz] = lp + lp0 - sp * LN2_C - (C0 + z0 * T0 + z1 * T1);
}

extern "C" void kernel_launch(void* const* d_in, const int* in_sizes, int n_in,
                              void* d_out, int out_size, void* d_ws, size_t ws_size,
                              hipStream_t stream) {
    const float* z     = (const float*)d_in[0];   // (512, 2, 2)
    const float* x     = (const float*)d_in[1];   // (512, 128)
    const float* theta = (const float*)d_in[2];   // (2, 128)
    float* ws  = (float*)d_ws;
    float* out = (float*)d_out;                   // (512, 2) float32

    hipLaunchKernelGGL(prep_kernel,  dim3(768),  dim3(256), 0, stream, z, x, theta, ws);
    hipLaunchKernelGGL(main_kernel,  dim3(1024), dim3(256), 0, stream, ws);
    hipLaunchKernelGGL(final_kernel, dim3(4),    dim3(256), 0, stream, z, theta, ws, out);
}